// Round 1
// baseline (1419.090 us; speedup 1.0000x reference)
//
#include <hip/hip_runtime.h>

// EnvelopeAR: e_t = (1-a_t) x_t + a_t e_{t-1},  a_t = s*aa + (1-s)*ar,
//             s = sigmoid(K (x_t - e_{t-1})),  K = 50, fs = 48000.
// Chunk-parallel with warm-up: contraction rate >= exp(-1/(tau_max*fs)),
// tau_max = 0.105 -> time const 5040 samples. W = 32768 -> err <= 1.5e-3.

#define ENV_FS 48000.0f
#define ENV_A  72.13475204444817f   /* K * log2(e), K = 50 */
#define ENV_W  32768                /* warm-up steps (multiple of 32) */
#define ENV_L  2048                 /* output chunk length (multiple of 32) */

static __device__ __forceinline__ float env_step(float e, float xt, float aa, float ar) {
    // u = exp(K*(e - x)) = 2^(A*e - A*x)
    float w   = __builtin_fmaf(ENV_A, e, -ENV_A * xt);   // chain op 1
    float u   = __builtin_amdgcn_exp2f(w);               // chain op 2
    float den = u + 1.0f;                                // chain op 3
    float num = __builtin_fmaf(ar, u, aa);               // off-chain
    float d   = e - xt;                                  // off-chain (parallel w/ op 1)
    float g   = num * d;                                 // off-chain
    float r   = __builtin_amdgcn_rcpf(den);              // chain op 4
    return __builtin_fmaf(g, r, xt);                     // chain op 5: x + alpha*(e-x)
}

__global__ __launch_bounds__(64, 1)
void EnvelopeAR_kernel(const float* __restrict__ x,
                       const float* __restrict__ tau_a,
                       const float* __restrict__ tau_r,
                       float* __restrict__ out,
                       int B, int T) {
    const int g = blockIdx.x * 64 + threadIdx.x;
    const int b = g % B;            // row   (lanes of a wave: consecutive rows, same chunk)
    const int c = g / B;            // chunk index

    const int out_start = c * ENV_L;
    if (out_start >= T) return;
    int t0 = out_start - ENV_W;
    if (t0 < 0) t0 = 0;             // clamped chunks are exact (true e0 = 0)
    int tend = out_start + ENV_L;
    if (tend > T) tend = T;

    const float* __restrict__ xr = x + (size_t)b * (size_t)T;
    float* __restrict__ orow     = out + (size_t)b * (size_t)T;

    const float aa = expf(-1.0f / (tau_a[b] * ENV_FS));
    const float ar = expf(-1.0f / (tau_r[b] * ENV_FS));

    float e = 0.0f;

    const float4* __restrict__ x4 = (const float4*)xr;
    float4* __restrict__ o4       = (float4*)orow;

    const int nblk = (tend - t0) >> 5;      // 32-step blocks (t0, out_start, tend all %32==0)
    float4 cur[8], nxt[8];

    if (nblk > 0) {
        const int base4 = t0 >> 2;
        #pragma unroll
        for (int i = 0; i < 8; ++i) cur[i] = x4[base4 + i];

        for (int blk = 0; blk < nblk; ++blk) {
            const int t  = t0 + (blk << 5);
            const int b4 = t >> 2;
            if (blk + 1 < nblk) {                 // prefetch next 32 samples (hides ~900 cyc)
                #pragma unroll
                for (int i = 0; i < 8; ++i) nxt[i] = x4[b4 + 8 + i];
            }
            const bool do_store = (t >= out_start);   // wave-uniform
            #pragma unroll
            for (int i = 0; i < 8; ++i) {
                const float4 xi = cur[i];
                float4 oo;
                e = env_step(e, xi.x, aa, ar); oo.x = e;
                e = env_step(e, xi.y, aa, ar); oo.y = e;
                e = env_step(e, xi.z, aa, ar); oo.z = e;
                e = env_step(e, xi.w, aa, ar); oo.w = e;
                if (do_store) o4[b4 + i] = oo;
            }
            #pragma unroll
            for (int i = 0; i < 8; ++i) cur[i] = nxt[i];
        }
    }

    // generic scalar tail (unused for T=65536, kept for safety)
    for (int t = t0 + (nblk << 5); t < tend; ++t) {
        e = env_step(e, xr[t], aa, ar);
        if (t >= out_start) orow[t] = e;
    }
}

extern "C" void kernel_launch(void* const* d_in, const int* in_sizes, int n_in,
                              void* d_out, int out_size, void* d_ws, size_t ws_size,
                              hipStream_t stream) {
    const float* x      = (const float*)d_in[0];
    const float* tau_a  = (const float*)d_in[1];
    const float* tau_r  = (const float*)d_in[2];
    float* out          = (float*)d_out;

    const int B = in_sizes[1];              // 256
    const int T = in_sizes[0] / B;          // 65536

    const int C = (T + ENV_L - 1) / ENV_L;  // chunks per row (32)
    const int total_threads = B * C;        // 8192
    const int block = 64;
    const int grid  = (total_threads + block - 1) / block;

    EnvelopeAR_kernel<<<grid, block, 0, stream>>>(x, tau_a, tau_r, out, B, T);
}

// Round 2
// 900.185 us; speedup vs baseline: 1.5764x; 1.5764x over previous
//
#include <hip/hip_runtime.h>
#include <math.h>

// EnvelopeAR: e_t = (1-a_t) x_t + a_t e_{t-1},  a_t = s*aa + (1-s)*ar,
//             s = sigmoid(K (x_t - e_{t-1})),  K = 50, fs = 48000.
// Chunk-parallel with warm-up. Contraction time-const <= 5040 samples
// (tau <= 0.105). W = 24576 -> truncation <= e^-4.88 ~ 7.6e-3 worst-case;
// measured fp drift ~3.5e-3; total ~1.1e-2 < 1.63e-2 threshold.
// Round-2 change: transpose x to [t][b] so each wave's 64 lanes
// (consecutive rows, same chunk) load one contiguous 256B line per sample;
// round-1's 256KB-stride scattered loads cost ~66 stall cyc/step.

#define ENV_FS 48000.0f
#define ENV_A  72.13475204444817f   /* K * log2(e), K = 50 */
#define ENV_W  24576                /* warm-up steps (multiple of 32) */
#define ENV_L  2048                 /* output chunk length (multiple of 32) */

static __device__ __forceinline__ float env_step(float e, float xt, float aa, float ar) {
    float w   = __builtin_fmaf(ENV_A, e, -ENV_A * xt);   // chain op 1 (-A*x off-chain)
    float u   = __builtin_amdgcn_exp2f(w);               // chain op 2
    float den = u + 1.0f;                                // chain op 3
    float num = __builtin_fmaf(ar, u, aa);               // off-chain vs rcp
    float d   = e - xt;                                  // off-chain
    float g   = num * d;                                 // overlaps rcp
    float r   = __builtin_amdgcn_rcpf(den);              // chain op 4
    return __builtin_fmaf(g, r, xt);                     // chain op 5
}

// ---------- transpose x[b][t] -> xT[t][b], 64x64 LDS tiles ----------
__global__ __launch_bounds__(256)
void env_transpose(const float* __restrict__ in, float* __restrict__ outT,
                   int B, int T) {
    __shared__ float tile[64][65];
    const int tb = blockIdx.x * 64;   // t tile base
    const int bb = blockIdx.y * 64;   // b tile base
    const int tx = threadIdx.x & 63;
    const int ty = threadIdx.x >> 6;  // 0..3
    #pragma unroll
    for (int i = ty; i < 64; i += 4)                       // read coalesced along t
        tile[i][tx] = in[(size_t)(bb + i) * T + tb + tx];
    __syncthreads();
    #pragma unroll
    for (int i = ty; i < 64; i += 4)                       // write coalesced along b
        outT[(size_t)(tb + i) * B + bb + tx] = tile[tx][i]; // stride-65: conflict-free
}

// ---------- chunk-parallel scan over transposed input ----------
__global__ __launch_bounds__(64, 1)
void env_compute_T(const float* __restrict__ xT,   // [T][B]
                   const float* __restrict__ tau_a,
                   const float* __restrict__ tau_r,
                   float* __restrict__ out,        // [B][T]
                   int B, int T) {
    const int g = blockIdx.x * 64 + threadIdx.x;
    const int b = g % B;            // lanes: 64 consecutive rows (B%64==0 -> no wrap)
    const int c = g / B;            // chunk index, wave-uniform

    const int out_start = c * ENV_L;
    if (out_start >= T) return;
    int t0 = out_start - ENV_W; if (t0 < 0) t0 = 0;   // clamped chunks exact
    int tend = out_start + ENV_L; if (tend > T) tend = T;

    const float aa = expf(-1.0f / (tau_a[b] * ENV_FS));
    const float ar = expf(-1.0f / (tau_r[b] * ENV_FS));

    float* __restrict__ orow = out + (size_t)b * (size_t)T;
    float4* __restrict__ o4  = (float4*)orow;

    float e = 0.0f;
    const int nblk = (tend - t0) >> 5;   // t0, out_start, tend all %32==0 here
    float bufA[32], bufB[32];            // static indexing only (no scratch)

#define ENV_LOAD(buf, tt) do { \
        const float* __restrict__ _p = xT + (size_t)(tt) * (size_t)B + (size_t)b; \
        _Pragma("unroll") \
        for (int _i = 0; _i < 32; ++_i) (buf)[_i] = _p[(size_t)_i * (size_t)B]; \
    } while (0)

#define ENV_COMP(buf, tt) do { \
        const bool _st = ((tt) >= out_start);  /* wave-uniform */ \
        _Pragma("unroll") \
        for (int _i = 0; _i < 8; ++_i) { \
            float4 _o; \
            _o.x = e = env_step(e, (buf)[4*_i+0], aa, ar); \
            _o.y = e = env_step(e, (buf)[4*_i+1], aa, ar); \
            _o.z = e = env_step(e, (buf)[4*_i+2], aa, ar); \
            _o.w = e = env_step(e, (buf)[4*_i+3], aa, ar); \
            if (_st) o4[((tt) >> 2) + _i] = _o; \
        } \
    } while (0)

    int t = t0, blk = 0;
    if (nblk > 0) {
        ENV_LOAD(bufA, t);
        for (;;) {
            if (blk + 1 < nblk) ENV_LOAD(bufB, t + 32);   // prefetch next block
            ENV_COMP(bufA, t);
            ++blk; t += 32;
            if (blk >= nblk) break;
            if (blk + 1 < nblk) ENV_LOAD(bufA, t + 32);
            ENV_COMP(bufB, t);
            ++blk; t += 32;
            if (blk >= nblk) break;
        }
    }
    for (; t < tend; ++t) {              // generic tail (unused for T=65536)
        e = env_step(e, xT[(size_t)t * (size_t)B + b], aa, ar);
        if (t >= out_start) orow[t] = e;
    }
#undef ENV_LOAD
#undef ENV_COMP
}

// ---------- fallback: round-1 direct kernel (non-64-multiple shapes / tiny ws) ----------
__global__ __launch_bounds__(64, 1)
void env_direct(const float* __restrict__ x,
                const float* __restrict__ tau_a,
                const float* __restrict__ tau_r,
                float* __restrict__ out,
                int B, int T) {
    const int g = blockIdx.x * 64 + threadIdx.x;
    const int b = g % B;
    const int c = g / B;
    const int out_start = c * ENV_L;
    if (out_start >= T || b >= B) return;
    int t0 = out_start - ENV_W; if (t0 < 0) t0 = 0;
    int tend = out_start + ENV_L; if (tend > T) tend = T;
    const float* __restrict__ xr = x + (size_t)b * (size_t)T;
    float* __restrict__ orow     = out + (size_t)b * (size_t)T;
    const float aa = expf(-1.0f / (tau_a[b] * ENV_FS));
    const float ar = expf(-1.0f / (tau_r[b] * ENV_FS));
    float e = 0.0f;
    for (int t = t0; t < tend; ++t) {
        e = env_step(e, xr[t], aa, ar);
        if (t >= out_start) orow[t] = e;
    }
}

extern "C" void kernel_launch(void* const* d_in, const int* in_sizes, int n_in,
                              void* d_out, int out_size, void* d_ws, size_t ws_size,
                              hipStream_t stream) {
    const float* x     = (const float*)d_in[0];
    const float* tau_a = (const float*)d_in[1];
    const float* tau_r = (const float*)d_in[2];
    float* out         = (float*)d_out;

    const int B = in_sizes[1];              // 256
    const int T = in_sizes[0] / B;          // 65536

    const int C = (T + ENV_L - 1) / ENV_L;  // 32 chunks/row
    const int total = B * C;                // 8192 threads

    const bool fast = (ws_size >= (size_t)B * (size_t)T * 4) &&
                      (B % 64 == 0) && (T % 64 == 0) && (total % 64 == 0);
    if (fast) {
        float* xT = (float*)d_ws;
        dim3 tgrid(T / 64, B / 64);
        env_transpose<<<tgrid, 256, 0, stream>>>(x, xT, B, T);
        env_compute_T<<<total / 64, 64, 0, stream>>>(xT, tau_a, tau_r, out, B, T);
    } else {
        env_direct<<<(total + 63) / 64, 64, 0, stream>>>(x, tau_a, tau_r, out, B, T);
    }
}